// Round 4
// baseline (1198.254 us; speedup 1.0000x reference)
//
#include <hip/hip_runtime.h>
#include <math.h>

typedef float f32x4 __attribute__((ext_vector_type(4)));

__device__ __forceinline__ float wsum64(float v) {
#pragma unroll
  for (int d = 1; d < 64; d <<= 1) v += __shfl_xor(v, d, 64);
  return v;
}

// Sparse-aware dense-row x dense-X product: acc[lane] = sum_k Arow[k] * X[k*64+lane].
// Streams the A row coalesced (64 lanes x float4 = 1KB/iter), ballots the nonzero
// mask (matrices are 0.1%-22% dense), and only touches X for actual nonzeros.
__device__ __forceinline__ float sprow(const float* __restrict__ Arow, int K,
                                       const float* __restrict__ X, int lane)
{
  float acc = 0.f;
  for (int k0 = 0; k0 < K; k0 += 256) {
    int k = k0 + lane * 4;
    f32x4 a = {0.f, 0.f, 0.f, 0.f};
    if (k + 4 <= K) {
      a = *(const f32x4*)(Arow + k);
    } else if (k < K) {
#pragma unroll
      for (int j = 0; j < 4; ++j)
        if (k + j < K) a[j] = Arow[k + j];
    }
    bool nz = (a[0] != 0.f) || (a[1] != 0.f) || (a[2] != 0.f) || (a[3] != 0.f);
    unsigned long long mask = __ballot(nz);
    while (mask) {
      int b = __ffsll(mask) - 1;
      mask &= mask - 1;
      float v0 = __shfl(a[0], b, 64);
      float v1 = __shfl(a[1], b, 64);
      float v2 = __shfl(a[2], b, 64);
      float v3 = __shfl(a[3], b, 64);
      int kb = k0 + b * 4;
      const float* Xp = X + (size_t)kb * 64 + lane;   // coalesced 256B row reads, L2-hot
      if (v0 != 0.f) acc = fmaf(v0, Xp[0],   acc);
      if (v1 != 0.f) acc = fmaf(v1, Xp[64],  acc);
      if (v2 != 0.f) acc = fmaf(v2, Xp[128], acc);
      if (v3 != 0.f) acc = fmaf(v3, Xp[192], acc);
    }
  }
  return acc;
}

// items0 = relu(A_i@itf) + relu(B_i@itf) + itf    (rows 0..3071)
__global__ __launch_bounds__(256) void spmm_items0(const float* __restrict__ Ai,
                                                   const float* __restrict__ Bi,
                                                   const float* __restrict__ itf,
                                                   float* __restrict__ items0)
{
  int r = blockIdx.x * 4 + (threadIdx.x >> 6);
  int lane = threadIdx.x & 63;
  float a1 = sprow(Ai + (size_t)r * 3072, 3072, itf, lane);
  float a2 = sprow(Bi + (size_t)r * 3072, 3072, itf, lane);
  items0[(size_t)r * 64 + lane] =
      fmaxf(a1, 0.f) + fmaxf(a2, 0.f) + itf[(size_t)r * 64 + lane];
}

// P = bi_avg @ items; bundles_f = relu(P)+bfeat -> fub0 rows 6000+; b1 = l2norm(relu(P))
__global__ __launch_bounds__(256) void spmm_bundle(const float* __restrict__ biA,
                                                   const float* __restrict__ items,
                                                   const float* __restrict__ bfeat,
                                                   float* __restrict__ fub0,
                                                   float* __restrict__ b1)
{
  int r = blockIdx.x * 4 + (threadIdx.x >> 6);
  int lane = threadIdx.x & 63;
  float acc = sprow(biA + (size_t)r * 3072, 3072, items, lane);
  float pv = fmaxf(acc, 0.f);
  fub0[(size_t)(6000 + r) * 64 + lane] = pv + bfeat[(size_t)r * 64 + lane];
  float n2 = wsum64(pv * pv);
  b1[(size_t)r * 64 + lane] = pv / fmaxf(sqrtf(n2), 1e-12f);
}

// users_f = relu(ui_avg@items) + relu(ub_avg@bundles_f) + ufeat -> fub0 rows 0..5999
__global__ __launch_bounds__(256) void spmm_users(const float* __restrict__ uiA,
                                                  const float* __restrict__ ubA,
                                                  const float* __restrict__ items,
                                                  const float* __restrict__ bundles_f,
                                                  const float* __restrict__ ufeat,
                                                  float* __restrict__ fub0)
{
  int r = blockIdx.x * 4 + (threadIdx.x >> 6);
  int lane = threadIdx.x & 63;
  float a1 = sprow(uiA + (size_t)r * 3072, 3072, items, lane);
  float a2 = sprow(ubA + (size_t)r * 3000, 3000, bundles_f, lane);
  fub0[(size_t)r * 64 + lane] =
      fmaxf(a1, 0.f) + fmaxf(a2, 0.f) + ufeat[(size_t)r * 64 + lane];
}

// Full tail fused into the ubg row product:
// f_ub = relu(ubg@f0W + b_ub); att2 fuse over {x0, x1}; joint l2norm; all_ub assembly.
__global__ __launch_bounds__(256) void spmm_ubg(const float* __restrict__ ubg,
                                                const float* __restrict__ f0W,
                                                const float* __restrict__ b_ub,
                                                const float* __restrict__ fub0,
                                                const float* __restrict__ b1,
                                                const float* __restrict__ att_w,
                                                float* __restrict__ all_ub)
{
  int r = blockIdx.x * 4 + (threadIdx.x >> 6);
  int lane = threadIdx.x & 63;
  float acc = sprow(ubg + (size_t)r * 9000, 9000, f0W, lane);
  float fu = fmaxf(acc + b_ub[lane], 0.f);
  float x0 = fub0[(size_t)r * 64 + lane];
  float x1 = (r < 6000) ? x0 : b1[(size_t)(r - 6000) * 64 + lane];
  float wv = att_w[lane];
  float s0 = wsum64(x0 * wv);
  float s1 = wsum64(x1 * wv);
  float m = fmaxf(s0, s1);
  float e0 = __expf(s0 - m), e1 = __expf(s1 - m);
  float fused = (e0 * x0 + e1 * x1) / (e0 + e1);
  float n2 = wsum64(fu * fu + fused * fused);
  float inv = 1.f / fmaxf(sqrtf(n2), 1e-12f);
  float* row = &all_ub[(size_t)r * 192];
  row[lane]        = x0;
  row[64 + lane]   = fu * inv;
  row[128 + lane]  = fused * inv;
}

// C[M x 64] = A[M x 64] @ W[64 x 64], f32, one wave per row. W staged in LDS.
__global__ __launch_bounds__(256) void rowgemm64(const float* __restrict__ A,
                                                 const float* __restrict__ W,
                                                 float* __restrict__ C, int M)
{
  __shared__ float Ws[64][64];
  for (int i = threadIdx.x; i < 1024; i += 256)
    ((f32x4*)&Ws[0][0])[i] = ((const f32x4*)W)[i];
  __syncthreads();
  int r = blockIdx.x * 4 + (threadIdx.x >> 6);
  int lane = threadIdx.x & 63;
  if (r >= M) return;
  float av = A[(size_t)r * 64 + lane];
  float acc = 0.f;
#pragma unroll
  for (int k = 0; k < 64; ++k)
    acc = fmaf(__shfl(av, k, 64), Ws[k][lane], acc);
  C[(size_t)r * 64 + lane] = acc;
}

// Q,K,V projections in one dispatch (blockIdx.y selects weight/output).
__global__ __launch_bounds__(256) void rowgemm64_qkv(const float* __restrict__ A,
                                                     const float* __restrict__ Wq,
                                                     const float* __restrict__ Wk,
                                                     const float* __restrict__ Wv,
                                                     float* __restrict__ qb,
                                                     float* __restrict__ kb,
                                                     float* __restrict__ vb)
{
  const float* W = (blockIdx.y == 0) ? Wq : (blockIdx.y == 1) ? Wk : Wv;
  float* C = (blockIdx.y == 0) ? qb : (blockIdx.y == 1) ? kb : vb;
  __shared__ float Ws[64][64];
  for (int i = threadIdx.x; i < 1024; i += 256)
    ((f32x4*)&Ws[0][0])[i] = ((const f32x4*)W)[i];
  __syncthreads();
  int r = blockIdx.x * 4 + (threadIdx.x >> 6);
  int lane = threadIdx.x & 63;
  float av = A[(size_t)r * 64 + lane];
  float acc = 0.f;
#pragma unroll
  for (int k = 0; k < 64; ++k)
    acc = fmaf(__shfl(av, k, 64), Ws[k][lane], acc);
  C[(size_t)r * 64 + lane] = acc;
}

// Flash attention: 8 heads, dh=8, n=3072. grid (96, 8), block 256 = 32 queries x 8 parts.
__global__ __launch_bounds__(256) void attn_kernel(const float* __restrict__ q,
                                                   const float* __restrict__ k,
                                                   const float* __restrict__ v,
                                                   float* __restrict__ o)
{
  __shared__ float Ks[256][8];
  __shared__ float Vs[256][8];
  const int h = blockIdx.y;
  const int tid = threadIdx.x;
  const int qi = tid >> 3, p = tid & 7;
  const int n = blockIdx.x * 32 + qi;

  float qr[8];
#pragma unroll
  for (int j = 0; j < 8; ++j) qr[j] = q[n * 64 + h * 8 + j] * 0.3535533905932738f;

  float mx = -1e30f, sum = 0.f, acc[8] = {};

  for (int m0 = 0; m0 < 3072; m0 += 256) {
    __syncthreads();
    {
      const float* kp = &k[(size_t)(m0 + tid) * 64 + h * 8];
      const float* vp = &v[(size_t)(m0 + tid) * 64 + h * 8];
      float4 a0 = *reinterpret_cast<const float4*>(kp);
      float4 a1 = *reinterpret_cast<const float4*>(kp + 4);
      float4 b0 = *reinterpret_cast<const float4*>(vp);
      float4 b1 = *reinterpret_cast<const float4*>(vp + 4);
      *reinterpret_cast<float4*>(&Ks[tid][0]) = a0;
      *reinterpret_cast<float4*>(&Ks[tid][4]) = a1;
      *reinterpret_cast<float4*>(&Vs[tid][0]) = b0;
      *reinterpret_cast<float4*>(&Vs[tid][4]) = b1;
    }
    __syncthreads();
    for (int mm = p; mm < 256; mm += 8) {
      float s = 0.f;
#pragma unroll
      for (int j = 0; j < 8; ++j) s = fmaf(qr[j], Ks[mm][j], s);
      float nm = fmaxf(mx, s);
      float corr = __expf(mx - nm);
      float w = __expf(s - nm);
      sum = sum * corr + w;
#pragma unroll
      for (int j = 0; j < 8; ++j) acc[j] = acc[j] * corr + w * Vs[mm][j];
      mx = nm;
    }
  }
#pragma unroll
  for (int d = 1; d < 8; d <<= 1) {
    float omx = __shfl_xor(mx, d, 64);
    float osum = __shfl_xor(sum, d, 64);
    float nm = fmaxf(mx, omx);
    float c1 = __expf(mx - nm), c2 = __expf(omx - nm);
    float nsum = sum * c1 + osum * c2;
#pragma unroll
    for (int j = 0; j < 8; ++j) {
      float oa = __shfl_xor(acc[j], d, 64);
      acc[j] = acc[j] * c1 + oa * c2;
    }
    mx = nm; sum = nsum;
  }
  if (p == 0) {
    float inv = 1.f / sum;
#pragma unroll
    for (int j = 0; j < 8; ++j) o[n * 64 + h * 8 + j] = acc[j] * inv;
  }
}

// Final gather + 576->8 relu MLP -> 1. One wave per batch row. grid 1024, block 256.
__global__ __launch_bounds__(256) void final_mlp(const float* __restrict__ all_ub,
                                                 const int* __restrict__ users,
                                                 const int* __restrict__ bundles,
                                                 const float* __restrict__ p1W,
                                                 const float* __restrict__ p1b,
                                                 const float* __restrict__ p2W,
                                                 const float* __restrict__ p2b,
                                                 float* __restrict__ out)
{
  __shared__ float W[576 * 8];
  for (int i = threadIdx.x; i < 576 * 8; i += 256) W[i] = p1W[i];
  __syncthreads();
  int j = blockIdx.x * 4 + (threadIdx.x >> 6);
  int lane = threadIdx.x & 63;
  const float* ue = &all_ub[(size_t)users[j] * 192];
  const float* be = &all_ub[(size_t)(6000 + bundles[j]) * 192];
  float hacc[8] = {};
#pragma unroll
  for (int db = 0; db < 9; ++db) {
    int d = db * 64 + lane;
    float ne;
    if (d < 192)      ne = ue[d] * be[d];
    else if (d < 384) ne = be[d - 192];
    else              ne = ue[d - 384];
#pragma unroll
    for (int h = 0; h < 8; ++h) hacc[h] = fmaf(ne, W[d * 8 + h], hacc[h]);
  }
#pragma unroll
  for (int d = 1; d < 64; d <<= 1)
#pragma unroll
    for (int h = 0; h < 8; ++h) hacc[h] += __shfl_xor(hacc[h], d, 64);
  if (lane == 0) {
    float o = p2b[0];
#pragma unroll
    for (int h = 0; h < 8; ++h) o += fmaxf(hacc[h] + p1b[h], 0.f) * p2W[h];
    out[j] = o;
  }
}

extern "C" void kernel_launch(void* const* d_in, const int* in_sizes, int n_in,
                              void* d_out, int out_size, void* d_ws, size_t ws_size,
                              hipStream_t stream)
{
  const float* ufeat   = (const float*)d_in[0];
  const float* ifeat   = (const float*)d_in[1];
  const float* bfeat   = (const float*)d_in[2];
  const float* Wq      = (const float*)d_in[3];
  const float* Wk      = (const float*)d_in[4];
  const float* Wv      = (const float*)d_in[5];
  const float* Wo      = (const float*)d_in[6];
  const float* W_ub    = (const float*)d_in[7];
  const float* b_ub    = (const float*)d_in[8];
  const float* att_b_w = (const float*)d_in[11];
  const float* p1W     = (const float*)d_in[13];
  const float* p1b     = (const float*)d_in[14];
  const float* p2W     = (const float*)d_in[15];
  const float* p2b     = (const float*)d_in[16];
  const float* A_i     = (const float*)d_in[17];
  const float* B_i     = (const float*)d_in[18];
  const float* bi_avg  = (const float*)d_in[19];
  const float* ui_avg  = (const float*)d_in[20];
  const float* ub_avg  = (const float*)d_in[21];
  const float* ubg     = (const float*)d_in[23];
  const int* users     = (const int*)d_in[25];
  const int* bundles   = (const int*)d_in[26];

  float* ws = (float*)d_ws;
  float* items0 = ws;  ws += 3072 * 64;
  float* qb     = ws;  ws += 3072 * 64;
  float* kb     = ws;  ws += 3072 * 64;
  float* vb     = ws;  ws += 3072 * 64;
  float* attnb  = ws;  ws += 3072 * 64;
  float* items  = ws;  ws += 3072 * 64;
  float* b1     = ws;  ws += 3000 * 64;
  float* fub0   = ws;  ws += 9000 * 64;   // users_f rows 0..5999, bundles_f 6000..8999
  float* f0W    = ws;  ws += 9000 * 64;   // fub0 @ W_ub
  float* all_ub = ws;  ws += 9000 * 192;

  // items0 = relu(A_i@itf) + relu(B_i@itf) + itf
  spmm_items0<<<768, 256, 0, stream>>>(A_i, B_i, ifeat, items0);

  // multi-head attention
  rowgemm64_qkv<<<dim3(768, 3), 256, 0, stream>>>(items0, Wq, Wk, Wv, qb, kb, vb);
  attn_kernel<<<dim3(96, 8), 256, 0, stream>>>(qb, kb, vb, attnb);
  rowgemm64<<<768, 256, 0, stream>>>(attnb, Wo, items, 3072);

  // bundles_f (+ b1), then users_f
  spmm_bundle<<<750, 256, 0, stream>>>(bi_avg, items, bfeat, fub0, b1);
  spmm_users<<<1500, 256, 0, stream>>>(ui_avg, ub_avg, items,
                                       fub0 + (size_t)6000 * 64, ufeat, fub0);

  // f0W = fub0 @ W_ub  (associativity: (G@F)@W == G@(F@W))
  rowgemm64<<<2250, 256, 0, stream>>>(fub0, W_ub, f0W, 9000);

  // ubg row product + bias/relu + att2 fuse + joint l2norm + all_ub assembly
  spmm_ubg<<<2250, 256, 0, stream>>>(ubg, f0W, b_ub, fub0, b1, att_b_w, all_ub);

  // gather + final MLP
  final_mlp<<<1024, 256, 0, stream>>>(all_ub, users, bundles, p1W, p1b, p2W, p2b,
                                      (float*)d_out);
}

// Round 5
// 933.247 us; speedup vs baseline: 1.2840x; 1.2840x over previous
//
#include <hip/hip_runtime.h>
#include <math.h>

typedef float f32x4 __attribute__((ext_vector_type(4)));

__device__ __forceinline__ float wsum64(float v) {
#pragma unroll
  for (int d = 1; d < 64; d <<= 1) v += __shfl_xor(v, d, 64);
  return v;
}

// One wave scans chunks {wave, wave+4, ...} of a K-length sparse row.
// Per 256-float chunk: coalesced float4 stream, ballot; if any nonzero,
// prefix-compact (col,val) pairs into this wave's LDS list, then consume
// with batched independent loads: acc[lane] += val * X[col*64+lane].
__device__ __forceinline__ float spseg(const float* __restrict__ Arow, int K,
                                       const float* __restrict__ X,
                                       int lane, int wave,
                                       uint2* __restrict__ L)
{
  float acc0 = 0.f, acc1 = 0.f;
  const int nch = (K + 255) >> 8;
  for (int c = wave; c < nch; c += 4) {
    const int k = (c << 8) + lane * 4;
    f32x4 a = {0.f, 0.f, 0.f, 0.f};
    if (k + 4 <= K) {
      a = *(const f32x4*)(Arow + k);
    } else {
#pragma unroll
      for (int j = 0; j < 4; ++j)
        if (k + j < K) a[j] = Arow[k + j];
    }
    const int n0 = (a[0] != 0.f), n1 = (a[1] != 0.f);
    const int n2 = (a[2] != 0.f), n3 = (a[3] != 0.f);
    const int cnt = n0 + n1 + n2 + n3;
    if (__ballot(cnt != 0) == 0ULL) continue;
    // inclusive prefix-scan of cnt across the wave
    int inc = cnt;
#pragma unroll
    for (int d = 1; d < 64; d <<= 1) {
      int t = __shfl_up(inc, d, 64);
      if (lane >= d) inc += t;
    }
    const int total = __shfl(inc, 63, 64);
    int p = inc - cnt;
    if (n0) { L[p] = make_uint2(k,     __float_as_uint(a[0])); p++; }
    if (n1) { L[p] = make_uint2(k + 1, __float_as_uint(a[1])); p++; }
    if (n2) { L[p] = make_uint2(k + 2, __float_as_uint(a[2])); p++; }
    if (n3) { L[p] = make_uint2(k + 3, __float_as_uint(a[3])); p++; }
    // wave-local visibility: this wave's ds_writes must land before reads
    asm volatile("s_waitcnt lgkmcnt(0)" ::: "memory");
    int e = 0;
    for (; e + 4 <= total; e += 4) {
      uint2 E0 = L[e], E1 = L[e + 1], E2 = L[e + 2], E3 = L[e + 3];
      float x0 = X[(E0.x << 6) | lane];
      float x1 = X[(E1.x << 6) | lane];
      float x2 = X[(E2.x << 6) | lane];
      float x3 = X[(E3.x << 6) | lane];
      acc0 = fmaf(__uint_as_float(E0.y), x0, acc0);
      acc1 = fmaf(__uint_as_float(E1.y), x1, acc1);
      acc0 = fmaf(__uint_as_float(E2.y), x2, acc0);
      acc1 = fmaf(__uint_as_float(E3.y), x3, acc1);
    }
    for (; e < total; ++e) {
      uint2 E = L[e];
      acc0 = fmaf(__uint_as_float(E.y), X[(E.x << 6) | lane], acc0);
    }
  }
  return acc0 + acc1;
}

// items0 = relu(A_i@itf) + relu(B_i@itf) + itf. One block per row (3072).
__global__ __launch_bounds__(256) void spmm_items0(const float* __restrict__ Ai,
                                                   const float* __restrict__ Bi,
                                                   const float* __restrict__ itf,
                                                   float* __restrict__ items0)
{
  __shared__ uint2 lists[4][256];
  __shared__ float red[4][2][64];
  const int r = blockIdx.x;
  const int lane = threadIdx.x & 63, wave = threadIdx.x >> 6;
  float sa = spseg(Ai + (size_t)r * 3072, 3072, itf, lane, wave, lists[wave]);
  float sb = spseg(Bi + (size_t)r * 3072, 3072, itf, lane, wave, lists[wave]);
  red[wave][0][lane] = sa;
  red[wave][1][lane] = sb;
  __syncthreads();
  if (threadIdx.x < 64) {
    float a1 = red[0][0][lane] + red[1][0][lane] + red[2][0][lane] + red[3][0][lane];
    float a2 = red[0][1][lane] + red[1][1][lane] + red[2][1][lane] + red[3][1][lane];
    items0[(size_t)r * 64 + lane] =
        fmaxf(a1, 0.f) + fmaxf(a2, 0.f) + itf[(size_t)r * 64 + lane];
  }
}

// P = bi_avg@items; bundles_f = relu(P)+bfeat -> fub0 rows 6000+; b1 = l2norm(relu(P)).
__global__ __launch_bounds__(256) void spmm_bundle(const float* __restrict__ biA,
                                                   const float* __restrict__ items,
                                                   const float* __restrict__ bfeat,
                                                   float* __restrict__ fub0,
                                                   float* __restrict__ b1)
{
  __shared__ uint2 lists[4][256];
  __shared__ float red[4][64];
  const int r = blockIdx.x;
  const int lane = threadIdx.x & 63, wave = threadIdx.x >> 6;
  float s = spseg(biA + (size_t)r * 3072, 3072, items, lane, wave, lists[wave]);
  red[wave][lane] = s;
  __syncthreads();
  if (threadIdx.x < 64) {
    float acc = red[0][lane] + red[1][lane] + red[2][lane] + red[3][lane];
    float pv = fmaxf(acc, 0.f);
    fub0[(size_t)(6000 + r) * 64 + lane] = pv + bfeat[(size_t)r * 64 + lane];
    float n2 = wsum64(pv * pv);
    b1[(size_t)r * 64 + lane] = pv / fmaxf(sqrtf(n2), 1e-12f);
  }
}

// users_f = relu(ui_avg@items) + relu(ub_avg@bundles_f) + ufeat -> fub0 rows 0..5999.
__global__ __launch_bounds__(256) void spmm_users(const float* __restrict__ uiA,
                                                  const float* __restrict__ ubA,
                                                  const float* __restrict__ items,
                                                  const float* __restrict__ bundles_f,
                                                  const float* __restrict__ ufeat,
                                                  float* __restrict__ fub0)
{
  __shared__ uint2 lists[4][256];
  __shared__ float red[4][2][64];
  const int r = blockIdx.x;
  const int lane = threadIdx.x & 63, wave = threadIdx.x >> 6;
  float sa = spseg(uiA + (size_t)r * 3072, 3072, items, lane, wave, lists[wave]);
  float sb = spseg(ubA + (size_t)r * 3000, 3000, bundles_f, lane, wave, lists[wave]);
  red[wave][0][lane] = sa;
  red[wave][1][lane] = sb;
  __syncthreads();
  if (threadIdx.x < 64) {
    float a1 = red[0][0][lane] + red[1][0][lane] + red[2][0][lane] + red[3][0][lane];
    float a2 = red[0][1][lane] + red[1][1][lane] + red[2][1][lane] + red[3][1][lane];
    fub0[(size_t)r * 64 + lane] =
        fmaxf(a1, 0.f) + fmaxf(a2, 0.f) + ufeat[(size_t)r * 64 + lane];
  }
}

// f_ub row = relu(ubg@f0W + b_ub); att2 fuse; joint l2norm; all_ub assembly.
__global__ __launch_bounds__(256) void spmm_ubg(const float* __restrict__ ubg,
                                                const float* __restrict__ f0W,
                                                const float* __restrict__ b_ub,
                                                const float* __restrict__ fub0,
                                                const float* __restrict__ b1,
                                                const float* __restrict__ att_w,
                                                float* __restrict__ all_ub)
{
  __shared__ uint2 lists[4][256];
  __shared__ float red[4][64];
  const int r = blockIdx.x;
  const int lane = threadIdx.x & 63, wave = threadIdx.x >> 6;
  float s = spseg(ubg + (size_t)r * 9000, 9000, f0W, lane, wave, lists[wave]);
  red[wave][lane] = s;
  __syncthreads();
  if (threadIdx.x < 64) {
    float acc = red[0][lane] + red[1][lane] + red[2][lane] + red[3][lane];
    float fu = fmaxf(acc + b_ub[lane], 0.f);
    float x0 = fub0[(size_t)r * 64 + lane];
    float x1 = (r < 6000) ? x0 : b1[(size_t)(r - 6000) * 64 + lane];
    float wv = att_w[lane];
    float s0 = wsum64(x0 * wv);
    float s1 = wsum64(x1 * wv);
    float m = fmaxf(s0, s1);
    float e0 = __expf(s0 - m), e1 = __expf(s1 - m);
    float fused = (e0 * x0 + e1 * x1) / (e0 + e1);
    float n2 = wsum64(fu * fu + fused * fused);
    float inv = 1.f / fmaxf(sqrtf(n2), 1e-12f);
    float* row = &all_ub[(size_t)r * 192];
    row[lane]       = x0;
    row[64 + lane]  = fu * inv;
    row[128 + lane] = fused * inv;
  }
}

// C[M x 64] = A[M x 64] @ W[64 x 64]; 4 rows/block; A row staged in LDS (broadcast reads).
__global__ __launch_bounds__(256) void rowgemm64(const float* __restrict__ A,
                                                 const float* __restrict__ W,
                                                 float* __restrict__ C, int M)
{
  __shared__ float Ws[64][64];
  __shared__ float As[4][64];
  for (int i = threadIdx.x; i < 1024; i += 256)
    ((f32x4*)&Ws[0][0])[i] = ((const f32x4*)W)[i];
  const int wave = threadIdx.x >> 6, lane = threadIdx.x & 63;
  const int r = blockIdx.x * 4 + wave;
  const bool valid = r < M;
  As[wave][lane] = valid ? A[(size_t)r * 64 + lane] : 0.f;
  __syncthreads();
  float acc = 0.f;
#pragma unroll
  for (int k = 0; k < 64; ++k)
    acc = fmaf(As[wave][k], Ws[k][lane], acc);
  if (valid) C[(size_t)r * 64 + lane] = acc;
}

// Q,K,V projections in one dispatch (blockIdx.y selects weight/output).
__global__ __launch_bounds__(256) void rowgemm64_qkv(const float* __restrict__ A,
                                                     const float* __restrict__ Wq,
                                                     const float* __restrict__ Wk,
                                                     const float* __restrict__ Wv,
                                                     float* __restrict__ qb,
                                                     float* __restrict__ kb,
                                                     float* __restrict__ vb)
{
  const float* W = (blockIdx.y == 0) ? Wq : (blockIdx.y == 1) ? Wk : Wv;
  float* C = (blockIdx.y == 0) ? qb : (blockIdx.y == 1) ? kb : vb;
  __shared__ float Ws[64][64];
  __shared__ float As[4][64];
  for (int i = threadIdx.x; i < 1024; i += 256)
    ((f32x4*)&Ws[0][0])[i] = ((const f32x4*)W)[i];
  const int wave = threadIdx.x >> 6, lane = threadIdx.x & 63;
  const int r = blockIdx.x * 4 + wave;
  As[wave][lane] = A[(size_t)r * 64 + lane];
  __syncthreads();
  float acc = 0.f;
#pragma unroll
  for (int k = 0; k < 64; ++k)
    acc = fmaf(As[wave][k], Ws[k][lane], acc);
  C[(size_t)r * 64 + lane] = acc;
}

// Flash attention: 8 heads, dh=8, n=3072. grid (96, 8), block 256 = 32 queries x 8 parts.
__global__ __launch_bounds__(256) void attn_kernel(const float* __restrict__ q,
                                                   const float* __restrict__ k,
                                                   const float* __restrict__ v,
                                                   float* __restrict__ o)
{
  __shared__ float Ks[256][8];
  __shared__ float Vs[256][8];
  const int h = blockIdx.y;
  const int tid = threadIdx.x;
  const int qi = tid >> 3, p = tid & 7;
  const int n = blockIdx.x * 32 + qi;

  float qr[8];
#pragma unroll
  for (int j = 0; j < 8; ++j) qr[j] = q[n * 64 + h * 8 + j] * 0.3535533905932738f;

  float mx = -1e30f, sum = 0.f, acc[8] = {};

  for (int m0 = 0; m0 < 3072; m0 += 256) {
    __syncthreads();
    {
      const float* kp = &k[(size_t)(m0 + tid) * 64 + h * 8];
      const float* vp = &v[(size_t)(m0 + tid) * 64 + h * 8];
      float4 a0 = *reinterpret_cast<const float4*>(kp);
      float4 a1 = *reinterpret_cast<const float4*>(kp + 4);
      float4 b0 = *reinterpret_cast<const float4*>(vp);
      float4 b1 = *reinterpret_cast<const float4*>(vp + 4);
      *reinterpret_cast<float4*>(&Ks[tid][0]) = a0;
      *reinterpret_cast<float4*>(&Ks[tid][4]) = a1;
      *reinterpret_cast<float4*>(&Vs[tid][0]) = b0;
      *reinterpret_cast<float4*>(&Vs[tid][4]) = b1;
    }
    __syncthreads();
    for (int mm = p; mm < 256; mm += 8) {
      float s = 0.f;
#pragma unroll
      for (int j = 0; j < 8; ++j) s = fmaf(qr[j], Ks[mm][j], s);
      float nm = fmaxf(mx, s);
      float corr = __expf(mx - nm);
      float w = __expf(s - nm);
      sum = sum * corr + w;
#pragma unroll
      for (int j = 0; j < 8; ++j) acc[j] = acc[j] * corr + w * Vs[mm][j];
      mx = nm;
    }
  }
#pragma unroll
  for (int d = 1; d < 8; d <<= 1) {
    float omx = __shfl_xor(mx, d, 64);
    float osum = __shfl_xor(sum, d, 64);
    float nm = fmaxf(mx, omx);
    float c1 = __expf(mx - nm), c2 = __expf(omx - nm);
    float nsum = sum * c1 + osum * c2;
#pragma unroll
    for (int j = 0; j < 8; ++j) {
      float oa = __shfl_xor(acc[j], d, 64);
      acc[j] = acc[j] * c1 + oa * c2;
    }
    mx = nm; sum = nsum;
  }
  if (p == 0) {
    float inv = 1.f / sum;
#pragma unroll
    for (int j = 0; j < 8; ++j) o[n * 64 + h * 8 + j] = acc[j] * inv;
  }
}

// Final gather + 576->8 relu MLP -> 1. One wave per batch row. grid 1024, block 256.
__global__ __launch_bounds__(256) void final_mlp(const float* __restrict__ all_ub,
                                                 const int* __restrict__ users,
                                                 const int* __restrict__ bundles,
                                                 const float* __restrict__ p1W,
                                                 const float* __restrict__ p1b,
                                                 const float* __restrict__ p2W,
                                                 const float* __restrict__ p2b,
                                                 float* __restrict__ out)
{
  __shared__ float W[576 * 8];
  for (int i = threadIdx.x; i < 576 * 8; i += 256) W[i] = p1W[i];
  __syncthreads();
  int j = blockIdx.x * 4 + (threadIdx.x >> 6);
  int lane = threadIdx.x & 63;
  const float* ue = &all_ub[(size_t)users[j] * 192];
  const float* be = &all_ub[(size_t)(6000 + bundles[j]) * 192];
  float hacc[8] = {};
#pragma unroll
  for (int db = 0; db < 9; ++db) {
    int d = db * 64 + lane;
    float ne;
    if (d < 192)      ne = ue[d] * be[d];
    else if (d < 384) ne = be[d - 192];
    else              ne = ue[d - 384];
#pragma unroll
    for (int h = 0; h < 8; ++h) hacc[h] = fmaf(ne, W[d * 8 + h], hacc[h]);
  }
#pragma unroll
  for (int d = 1; d < 64; d <<= 1)
#pragma unroll
    for (int h = 0; h < 8; ++h) hacc[h] += __shfl_xor(hacc[h], d, 64);
  if (lane == 0) {
    float o = p2b[0];
#pragma unroll
    for (int h = 0; h < 8; ++h) o += fmaxf(hacc[h] + p1b[h], 0.f) * p2W[h];
    out[j] = o;
  }
}

extern "C" void kernel_launch(void* const* d_in, const int* in_sizes, int n_in,
                              void* d_out, int out_size, void* d_ws, size_t ws_size,
                              hipStream_t stream)
{
  const float* ufeat   = (const float*)d_in[0];
  const float* ifeat   = (const float*)d_in[1];
  const float* bfeat   = (const float*)d_in[2];
  const float* Wq      = (const float*)d_in[3];
  const float* Wk      = (const float*)d_in[4];
  const float* Wv      = (const float*)d_in[5];
  const float* Wo      = (const float*)d_in[6];
  const float* W_ub    = (const float*)d_in[7];
  const float* b_ub    = (const float*)d_in[8];
  const float* att_b_w = (const float*)d_in[11];
  const float* p1W     = (const float*)d_in[13];
  const float* p1b     = (const float*)d_in[14];
  const float* p2W     = (const float*)d_in[15];
  const float* p2b     = (const float*)d_in[16];
  const float* A_i     = (const float*)d_in[17];
  const float* B_i     = (const float*)d_in[18];
  const float* bi_avg  = (const float*)d_in[19];
  const float* ui_avg  = (const float*)d_in[20];
  const float* ub_avg  = (const float*)d_in[21];
  const float* ubg     = (const float*)d_in[23];
  const int* users     = (const int*)d_in[25];
  const int* bundles   = (const int*)d_in[26];

  float* ws = (float*)d_ws;
  float* items0 = ws;  ws += 3072 * 64;
  float* qb     = ws;  ws += 3072 * 64;
  float* kb     = ws;  ws += 3072 * 64;
  float* vb     = ws;  ws += 3072 * 64;
  float* attnb  = ws;  ws += 3072 * 64;
  float* items  = ws;  ws += 3072 * 64;
  float* b1     = ws;  ws += 3000 * 64;
  float* fub0   = ws;  ws += 9000 * 64;   // users_f rows 0..5999, bundles_f 6000..8999
  float* f0W    = ws;  ws += 9000 * 64;   // fub0 @ W_ub
  float* all_ub = ws;  ws += 9000 * 192;

  // items0 = relu(A_i@itf) + relu(B_i@itf) + itf
  spmm_items0<<<3072, 256, 0, stream>>>(A_i, B_i, ifeat, items0);

  // multi-head attention
  rowgemm64_qkv<<<dim3(768, 3), 256, 0, stream>>>(items0, Wq, Wk, Wv, qb, kb, vb);
  attn_kernel<<<dim3(96, 8), 256, 0, stream>>>(qb, kb, vb, attnb);
  rowgemm64<<<768, 256, 0, stream>>>(attnb, Wo, items, 3072);

  // bundles_f (+ b1), then users_f
  spmm_bundle<<<3000, 256, 0, stream>>>(bi_avg, items, bfeat, fub0, b1);
  spmm_users<<<6000, 256, 0, stream>>>(ui_avg, ub_avg, items,
                                       fub0 + (size_t)6000 * 64, ufeat, fub0);

  // f0W = fub0 @ W_ub  (associativity: (G@F)@W == G@(F@W))
  rowgemm64<<<2250, 256, 0, stream>>>(fub0, W_ub, f0W, 9000);

  // ubg row product + bias/relu + att2 fuse + joint l2norm + all_ub assembly
  spmm_ubg<<<9000, 256, 0, stream>>>(ubg, f0W, b_ub, fub0, b1, att_b_w, all_ub);

  // gather + final MLP
  final_mlp<<<1024, 256, 0, stream>>>(all_ub, users, bundles, p1W, p1b, p2W, p2b,
                                      (float*)d_out);
}

// Round 6
// 915.061 us; speedup vs baseline: 1.3095x; 1.0199x over previous
//
#include <hip/hip_runtime.h>
#include <math.h>

typedef float f32x4 __attribute__((ext_vector_type(4)));

__device__ __forceinline__ float wsum64(float v) {
#pragma unroll
  for (int d = 1; d < 64; d <<= 1) v += __shfl_xor(v, d, 64);
  return v;
}

__device__ __forceinline__ f32x4 ldchunk(const float* __restrict__ Arow, int K,
                                         int c, int lane)
{
  const int k = (c << 8) + lane * 4;
  f32x4 a = {0.f, 0.f, 0.f, 0.f};
  if (k + 4 <= K) {
    a = *(const f32x4*)(Arow + k);
  } else if (k < K) {
#pragma unroll
    for (int j = 0; j < 4; ++j)
      if (k + j < K) a[j] = Arow[k + j];
  }
  return a;
}

// One wave scans chunks {wave, wave+4, ...} of a K-length sparse row, with the
// next chunk's 1KB load issued BEFORE the current chunk is processed (prefetch
// hides HBM latency under ballot/compact/consume). Nonzeros are prefix-compacted
// into a wave-private LDS list, then consumed with batched independent L2 loads:
// acc[lane] += val * X[col*64+lane].
__device__ __forceinline__ float spseg(const float* __restrict__ Arow, int K,
                                       const float* __restrict__ X,
                                       int lane, int wave,
                                       uint2* __restrict__ L)
{
  float acc0 = 0.f, acc1 = 0.f;
  const int nch = (K + 255) >> 8;
  int c = wave;
  if (c >= nch) return 0.f;
  f32x4 a = ldchunk(Arow, K, c, lane);
  while (c < nch) {
    const int cn = c + 4;
    f32x4 an = {0.f, 0.f, 0.f, 0.f};
    if (cn < nch) an = ldchunk(Arow, K, cn, lane);   // prefetch next chunk

    const int k = (c << 8) + lane * 4;
    const int n0 = (a[0] != 0.f), n1 = (a[1] != 0.f);
    const int n2 = (a[2] != 0.f), n3 = (a[3] != 0.f);
    const int cnt = n0 + n1 + n2 + n3;
    if (__ballot(cnt != 0) != 0ULL) {
      // inclusive prefix-scan of cnt across the wave
      int inc = cnt;
#pragma unroll
      for (int d = 1; d < 64; d <<= 1) {
        int t = __shfl_up(inc, d, 64);
        if (lane >= d) inc += t;
      }
      const int total = __shfl(inc, 63, 64);
      int p = inc - cnt;
      if (n0) { L[p] = make_uint2(k,     __float_as_uint(a[0])); p++; }
      if (n1) { L[p] = make_uint2(k + 1, __float_as_uint(a[1])); p++; }
      if (n2) { L[p] = make_uint2(k + 2, __float_as_uint(a[2])); p++; }
      if (n3) { L[p] = make_uint2(k + 3, __float_as_uint(a[3])); p++; }
      // wave-local visibility of this wave's ds_writes
      asm volatile("s_waitcnt lgkmcnt(0)" ::: "memory");
      int e = 0;
      for (; e + 4 <= total; e += 4) {
        uint2 E0 = L[e], E1 = L[e + 1], E2 = L[e + 2], E3 = L[e + 3];
        float x0 = X[(E0.x << 6) | lane];
        float x1 = X[(E1.x << 6) | lane];
        float x2 = X[(E2.x << 6) | lane];
        float x3 = X[(E3.x << 6) | lane];
        acc0 = fmaf(__uint_as_float(E0.y), x0, acc0);
        acc1 = fmaf(__uint_as_float(E1.y), x1, acc1);
        acc0 = fmaf(__uint_as_float(E2.y), x2, acc0);
        acc1 = fmaf(__uint_as_float(E3.y), x3, acc1);
      }
      for (; e < total; ++e) {
        uint2 E = L[e];
        acc0 = fmaf(__uint_as_float(E.y), X[(E.x << 6) | lane], acc0);
      }
    }
    a = an;
    c = cn;
  }
  return acc0 + acc1;
}

// items0 = relu(A_i@itf) + relu(B_i@itf) + itf. One block per row (3072).
__global__ __launch_bounds__(256) void spmm_items0(const float* __restrict__ Ai,
                                                   const float* __restrict__ Bi,
                                                   const float* __restrict__ itf,
                                                   float* __restrict__ items0)
{
  __shared__ uint2 lists[4][256];
  __shared__ float red[4][2][64];
  const int r = blockIdx.x;
  const int lane = threadIdx.x & 63, wave = threadIdx.x >> 6;
  float sa = spseg(Ai + (size_t)r * 3072, 3072, itf, lane, wave, lists[wave]);
  float sb = spseg(Bi + (size_t)r * 3072, 3072, itf, lane, wave, lists[wave]);
  red[wave][0][lane] = sa;
  red[wave][1][lane] = sb;
  __syncthreads();
  if (threadIdx.x < 64) {
    float a1 = red[0][0][lane] + red[1][0][lane] + red[2][0][lane] + red[3][0][lane];
    float a2 = red[0][1][lane] + red[1][1][lane] + red[2][1][lane] + red[3][1][lane];
    items0[(size_t)r * 64 + lane] =
        fmaxf(a1, 0.f) + fmaxf(a2, 0.f) + itf[(size_t)r * 64 + lane];
  }
}

// P = bi_avg@items; bundles_f = relu(P)+bfeat -> fub0 rows 6000+; b1 = l2norm(relu(P));
// fused: f0W row 6000+r = bundles_f_row @ W_ub.
__global__ __launch_bounds__(256) void spmm_bundle(const float* __restrict__ biA,
                                                   const float* __restrict__ items,
                                                   const float* __restrict__ bfeat,
                                                   const float* __restrict__ W_ub,
                                                   float* __restrict__ fub0,
                                                   float* __restrict__ b1,
                                                   float* __restrict__ f0W)
{
  __shared__ uint2 lists[4][256];
  __shared__ float red[4][64];
  __shared__ float rowsh[64];
  const int r = blockIdx.x;
  const int lane = threadIdx.x & 63, wave = threadIdx.x >> 6;
  float s = spseg(biA + (size_t)r * 3072, 3072, items, lane, wave, lists[wave]);
  red[wave][lane] = s;
  __syncthreads();
  if (threadIdx.x < 64) {
    float acc = red[0][lane] + red[1][lane] + red[2][lane] + red[3][lane];
    float pv = fmaxf(acc, 0.f);
    float fv = pv + bfeat[(size_t)r * 64 + lane];
    fub0[(size_t)(6000 + r) * 64 + lane] = fv;
    float n2 = wsum64(pv * pv);
    b1[(size_t)r * 64 + lane] = pv / fmaxf(sqrtf(n2), 1e-12f);
    rowsh[lane] = fv;
    asm volatile("s_waitcnt lgkmcnt(0)" ::: "memory");
    float w0 = 0.f, w1 = 0.f;
#pragma unroll
    for (int k = 0; k < 64; k += 2) {
      w0 = fmaf(rowsh[k],     W_ub[k * 64 + lane],       w0);
      w1 = fmaf(rowsh[k + 1], W_ub[(k + 1) * 64 + lane], w1);
    }
    f0W[(size_t)(6000 + r) * 64 + lane] = w0 + w1;
  }
}

// users_f = relu(ui_avg@items) + relu(ub_avg@bundles_f) + ufeat -> fub0 rows 0..5999;
// fused: f0W row r = users_f_row @ W_ub.
__global__ __launch_bounds__(256) void spmm_users(const float* __restrict__ uiA,
                                                  const float* __restrict__ ubA,
                                                  const float* __restrict__ items,
                                                  const float* __restrict__ bundles_f,
                                                  const float* __restrict__ ufeat,
                                                  const float* __restrict__ W_ub,
                                                  float* __restrict__ fub0,
                                                  float* __restrict__ f0W)
{
  __shared__ uint2 lists[4][256];
  __shared__ float red[4][2][64];
  __shared__ float rowsh[64];
  const int r = blockIdx.x;
  const int lane = threadIdx.x & 63, wave = threadIdx.x >> 6;
  float sa = spseg(uiA + (size_t)r * 3072, 3072, items, lane, wave, lists[wave]);
  float sb = spseg(ubA + (size_t)r * 3000, 3000, bundles_f, lane, wave, lists[wave]);
  red[wave][0][lane] = sa;
  red[wave][1][lane] = sb;
  __syncthreads();
  if (threadIdx.x < 64) {
    float a1 = red[0][0][lane] + red[1][0][lane] + red[2][0][lane] + red[3][0][lane];
    float a2 = red[0][1][lane] + red[1][1][lane] + red[2][1][lane] + red[3][1][lane];
    float fv = fmaxf(a1, 0.f) + fmaxf(a2, 0.f) + ufeat[(size_t)r * 64 + lane];
    fub0[(size_t)r * 64 + lane] = fv;
    rowsh[lane] = fv;
    asm volatile("s_waitcnt lgkmcnt(0)" ::: "memory");
    float w0 = 0.f, w1 = 0.f;
#pragma unroll
    for (int k = 0; k < 64; k += 2) {
      w0 = fmaf(rowsh[k],     W_ub[k * 64 + lane],       w0);
      w1 = fmaf(rowsh[k + 1], W_ub[(k + 1) * 64 + lane], w1);
    }
    f0W[(size_t)r * 64 + lane] = w0 + w1;
  }
}

// f_ub row = relu(ubg@f0W + b_ub); att2 fuse; joint l2norm; all_ub assembly.
__global__ __launch_bounds__(256) void spmm_ubg(const float* __restrict__ ubg,
                                                const float* __restrict__ f0W,
                                                const float* __restrict__ b_ub,
                                                const float* __restrict__ fub0,
                                                const float* __restrict__ b1,
                                                const float* __restrict__ att_w,
                                                float* __restrict__ all_ub)
{
  __shared__ uint2 lists[4][256];
  __shared__ float red[4][64];
  const int r = blockIdx.x;
  const int lane = threadIdx.x & 63, wave = threadIdx.x >> 6;
  float s = spseg(ubg + (size_t)r * 9000, 9000, f0W, lane, wave, lists[wave]);
  red[wave][lane] = s;
  __syncthreads();
  if (threadIdx.x < 64) {
    float acc = red[0][lane] + red[1][lane] + red[2][lane] + red[3][lane];
    float fu = fmaxf(acc + b_ub[lane], 0.f);
    float x0 = fub0[(size_t)r * 64 + lane];
    float x1 = (r < 6000) ? x0 : b1[(size_t)(r - 6000) * 64 + lane];
    float wv = att_w[lane];
    float s0 = wsum64(x0 * wv);
    float s1 = wsum64(x1 * wv);
    float m = fmaxf(s0, s1);
    float e0 = __expf(s0 - m), e1 = __expf(s1 - m);
    float fused = (e0 * x0 + e1 * x1) / (e0 + e1);
    float n2 = wsum64(fu * fu + fused * fused);
    float inv = 1.f / fmaxf(sqrtf(n2), 1e-12f);
    float* row = &all_ub[(size_t)r * 192];
    row[lane]       = x0;
    row[64 + lane]  = fu * inv;
    row[128 + lane] = fused * inv;
  }
}

// C[M x 64] = A[M x 64] @ W[64 x 64]; 4 rows/block; A row staged in LDS.
__global__ __launch_bounds__(256) void rowgemm64(const float* __restrict__ A,
                                                 const float* __restrict__ W,
                                                 float* __restrict__ C, int M)
{
  __shared__ float Ws[64][64];
  __shared__ float As[4][64];
  for (int i = threadIdx.x; i < 1024; i += 256)
    ((f32x4*)&Ws[0][0])[i] = ((const f32x4*)W)[i];
  const int wave = threadIdx.x >> 6, lane = threadIdx.x & 63;
  const int r = blockIdx.x * 4 + wave;
  const bool valid = r < M;
  As[wave][lane] = valid ? A[(size_t)r * 64 + lane] : 0.f;
  __syncthreads();
  float acc = 0.f;
#pragma unroll
  for (int k = 0; k < 64; ++k)
    acc = fmaf(As[wave][k], Ws[k][lane], acc);
  if (valid) C[(size_t)r * 64 + lane] = acc;
}

// Q,K,V projections in one dispatch (blockIdx.y selects weight/output).
__global__ __launch_bounds__(256) void rowgemm64_qkv(const float* __restrict__ A,
                                                     const float* __restrict__ Wq,
                                                     const float* __restrict__ Wk,
                                                     const float* __restrict__ Wv,
                                                     float* __restrict__ qb,
                                                     float* __restrict__ kb,
                                                     float* __restrict__ vb)
{
  const float* W = (blockIdx.y == 0) ? Wq : (blockIdx.y == 1) ? Wk : Wv;
  float* C = (blockIdx.y == 0) ? qb : (blockIdx.y == 1) ? kb : vb;
  __shared__ float Ws[64][64];
  __shared__ float As[4][64];
  for (int i = threadIdx.x; i < 1024; i += 256)
    ((f32x4*)&Ws[0][0])[i] = ((const f32x4*)W)[i];
  const int wave = threadIdx.x >> 6, lane = threadIdx.x & 63;
  const int r = blockIdx.x * 4 + wave;
  As[wave][lane] = A[(size_t)r * 64 + lane];
  __syncthreads();
  float acc = 0.f;
#pragma unroll
  for (int k = 0; k < 64; ++k)
    acc = fmaf(As[wave][k], Ws[k][lane], acc);
  C[(size_t)r * 64 + lane] = acc;
}

// Flash attention: 8 heads, dh=8, n=3072. grid (96, 8), block 256 = 32 queries x 8 parts.
// Batched: per 256-key LDS block, each part computes its 32 scores into registers,
// takes a block max, and does ONE rescale + 32-wide weighted PV accumulate.
__global__ __launch_bounds__(256) void attn_kernel(const float* __restrict__ q,
                                                   const float* __restrict__ k,
                                                   const float* __restrict__ v,
                                                   float* __restrict__ o)
{
  __shared__ float Ks[256][8];
  __shared__ float Vs[256][8];
  const int h = blockIdx.y;
  const int tid = threadIdx.x;
  const int qi = tid >> 3, p = tid & 7;
  const int n = blockIdx.x * 32 + qi;

  float qr[8];
#pragma unroll
  for (int j = 0; j < 8; ++j) qr[j] = q[n * 64 + h * 8 + j] * 0.3535533905932738f;

  float mx = -1e30f, sum = 0.f, acc[8] = {};

  for (int m0 = 0; m0 < 3072; m0 += 256) {
    __syncthreads();
    {
      const float* kp = &k[(size_t)(m0 + tid) * 64 + h * 8];
      const float* vp = &v[(size_t)(m0 + tid) * 64 + h * 8];
      float4 a0 = *reinterpret_cast<const float4*>(kp);
      float4 a1 = *reinterpret_cast<const float4*>(kp + 4);
      float4 b0 = *reinterpret_cast<const float4*>(vp);
      float4 b1 = *reinterpret_cast<const float4*>(vp + 4);
      *reinterpret_cast<float4*>(&Ks[tid][0]) = a0;
      *reinterpret_cast<float4*>(&Ks[tid][4]) = a1;
      *reinterpret_cast<float4*>(&Vs[tid][0]) = b0;
      *reinterpret_cast<float4*>(&Vs[tid][4]) = b1;
    }
    __syncthreads();

    float s[32];
#pragma unroll
    for (int i = 0; i < 32; ++i) {
      const int mm = p + i * 8;
      float t = 0.f;
#pragma unroll
      for (int j = 0; j < 8; ++j) t = fmaf(qr[j], Ks[mm][j], t);
      s[i] = t;
    }
    float lmax = s[0];
#pragma unroll
    for (int i = 1; i < 32; ++i) lmax = fmaxf(lmax, s[i]);
    const float nm = fmaxf(mx, lmax);
    const float corr = __expf(mx - nm);
    sum *= corr;
#pragma unroll
    for (int j = 0; j < 8; ++j) acc[j] *= corr;
#pragma unroll
    for (int i = 0; i < 32; ++i) {
      const int mm = p + i * 8;
      const float w = __expf(s[i] - nm);
      sum += w;
#pragma unroll
      for (int j = 0; j < 8; ++j) acc[j] = fmaf(w, Vs[mm][j], acc[j]);
    }
    mx = nm;
  }
  // merge the 8 partials (lanes differing in bits 0..2 share a query)
#pragma unroll
  for (int d = 1; d < 8; d <<= 1) {
    float omx = __shfl_xor(mx, d, 64);
    float osum = __shfl_xor(sum, d, 64);
    float nm = fmaxf(mx, omx);
    float c1 = __expf(mx - nm), c2 = __expf(omx - nm);
    float nsum = sum * c1 + osum * c2;
#pragma unroll
    for (int j = 0; j < 8; ++j) {
      float oa = __shfl_xor(acc[j], d, 64);
      acc[j] = acc[j] * c1 + oa * c2;
    }
    mx = nm; sum = nsum;
  }
  if (p == 0) {
    float inv = 1.f / sum;
#pragma unroll
    for (int j = 0; j < 8; ++j) o[n * 64 + h * 8 + j] = acc[j] * inv;
  }
}

// Final gather + 576->8 relu MLP -> 1. One wave per batch row. grid 1024, block 256.
__global__ __launch_bounds__(256) void final_mlp(const float* __restrict__ all_ub,
                                                 const int* __restrict__ users,
                                                 const int* __restrict__ bundles,
                                                 const float* __restrict__ p1W,
                                                 const float* __restrict__ p1b,
                                                 const float* __restrict__ p2W,
                                                 const float* __restrict__ p2b,
                                                 float* __restrict__ out)
{
  __shared__ float W[576 * 8];
  for (int i = threadIdx.x; i < 576 * 8; i += 256) W[i] = p1W[i];
  __syncthreads();
  int j = blockIdx.x * 4 + (threadIdx.x >> 6);
  int lane = threadIdx.x & 63;
  const float* ue = &all_ub[(size_t)users[j] * 192];
  const float* be = &all_ub[(size_t)(6000 + bundles[j]) * 192];
  float hacc[8] = {};
#pragma unroll
  for (int db = 0; db < 9; ++db) {
    int d = db * 64 + lane;
    float ne;
    if (d < 192)      ne = ue[d] * be[d];
    else if (d < 384) ne = be[d - 192];
    else              ne = ue[d - 384];
#pragma unroll
    for (int h = 0; h < 8; ++h) hacc[h] = fmaf(ne, W[d * 8 + h], hacc[h]);
  }
#pragma unroll
  for (int d = 1; d < 64; d <<= 1)
#pragma unroll
    for (int h = 0; h < 8; ++h) hacc[h] += __shfl_xor(hacc[h], d, 64);
  if (lane == 0) {
    float o = p2b[0];
#pragma unroll
    for (int h = 0; h < 8; ++h) o += fmaxf(hacc[h] + p1b[h], 0.f) * p2W[h];
    out[j] = o;
  }
}

extern "C" void kernel_launch(void* const* d_in, const int* in_sizes, int n_in,
                              void* d_out, int out_size, void* d_ws, size_t ws_size,
                              hipStream_t stream)
{
  const float* ufeat   = (const float*)d_in[0];
  const float* ifeat   = (const float*)d_in[1];
  const float* bfeat   = (const float*)d_in[2];
  const float* Wq      = (const float*)d_in[3];
  const float* Wk      = (const float*)d_in[4];
  const float* Wv      = (const float*)d_in[5];
  const float* Wo      = (const float*)d_in[6];
  const float* W_ub    = (const float*)d_in[7];
  const float* b_ub    = (const float*)d_in[8];
  const float* att_b_w = (const float*)d_in[11];
  const float* p1W     = (const float*)d_in[13];
  const float* p1b     = (const float*)d_in[14];
  const float* p2W     = (const float*)d_in[15];
  const float* p2b     = (const float*)d_in[16];
  const float* A_i     = (const float*)d_in[17];
  const float* B_i     = (const float*)d_in[18];
  const float* bi_avg  = (const float*)d_in[19];
  const float* ui_avg  = (const float*)d_in[20];
  const float* ub_avg  = (const float*)d_in[21];
  const float* ubg     = (const float*)d_in[23];
  const int* users     = (const int*)d_in[25];
  const int* bundles   = (const int*)d_in[26];

  float* ws = (float*)d_ws;
  float* items0 = ws;  ws += 3072 * 64;
  float* qb     = ws;  ws += 3072 * 64;
  float* kb     = ws;  ws += 3072 * 64;
  float* vb     = ws;  ws += 3072 * 64;
  float* attnb  = ws;  ws += 3072 * 64;
  float* items  = ws;  ws += 3072 * 64;
  float* b1     = ws;  ws += 3000 * 64;
  float* fub0   = ws;  ws += 9000 * 64;   // users_f rows 0..5999, bundles_f 6000..8999
  float* f0W    = ws;  ws += 9000 * 64;   // fub0 @ W_ub
  float* all_ub = ws;  ws += 9000 * 192;

  // items0 = relu(A_i@itf) + relu(B_i@itf) + itf
  spmm_items0<<<3072, 256, 0, stream>>>(A_i, B_i, ifeat, items0);

  // multi-head attention
  rowgemm64_qkv<<<dim3(768, 3), 256, 0, stream>>>(items0, Wq, Wk, Wv, qb, kb, vb);
  attn_kernel<<<dim3(96, 8), 256, 0, stream>>>(qb, kb, vb, attnb);
  rowgemm64<<<768, 256, 0, stream>>>(attnb, Wo, items, 3072);

  // bundles_f (+ b1, + f0W rows 6000+), then users_f (+ f0W rows 0..5999)
  spmm_bundle<<<3000, 256, 0, stream>>>(bi_avg, items, bfeat, W_ub, fub0, b1, f0W);
  spmm_users<<<6000, 256, 0, stream>>>(ui_avg, ub_avg, items,
                                       fub0 + (size_t)6000 * 64, ufeat, W_ub,
                                       fub0, f0W);

  // ubg row product + bias/relu + att2 fuse + joint l2norm + all_ub assembly
  spmm_ubg<<<9000, 256, 0, stream>>>(ubg, f0W, b_ub, fub0, b1, att_b_w, all_ub);

  // gather + final MLP
  final_mlp<<<1024, 256, 0, stream>>>(all_ub, users, bundles, p1W, p1b, p2W, p2b,
                                      (float*)d_out);
}

// Round 7
// 911.525 us; speedup vs baseline: 1.3146x; 1.0039x over previous
//
#include <hip/hip_runtime.h>
#include <math.h>

typedef float f32x4 __attribute__((ext_vector_type(4)));

__device__ __forceinline__ float wsum64(float v) {
#pragma unroll
  for (int d = 1; d < 64; d <<= 1) v += __shfl_xor(v, d, 64);
  return v;
}

__device__ __forceinline__ f32x4 ldchunk(const float* __restrict__ Arow, int K,
                                         int c, int lane)
{
  const int k = (c << 8) + lane * 4;
  f32x4 a = {0.f, 0.f, 0.f, 0.f};
  if (k + 4 <= K) {
    a = *(const f32x4*)(Arow + k);
  } else if (k < K) {
#pragma unroll
    for (int j = 0; j < 4; ++j)
      if (k + j < K) a[j] = Arow[k + j];
  }
  return a;
}

// One wave scans chunks {wave, wave+4, ...} of a K-length sparse row with a
// 2-deep prefetch pipeline (two 1KB loads in flight per wave; prefetches are
// issued BEFORE the empty-chunk skip so the pipeline never drains on sparse
// rows). Nonzeros are prefix-compacted into a wave-private LDS list, then
// consumed 8-at-a-time with 4 accumulators: acc[lane] += val * X[col*64+lane].
__device__ __forceinline__ float spseg(const float* __restrict__ Arow, int K,
                                       const float* __restrict__ X,
                                       int lane, int wave,
                                       uint2* __restrict__ L)
{
  float acc0 = 0.f, acc1 = 0.f, acc2 = 0.f, acc3 = 0.f;
  const int nch = (K + 255) >> 8;
  if (wave >= nch) return 0.f;
  f32x4 cur = ldchunk(Arow, K, wave, lane);
  f32x4 nxt = {0.f, 0.f, 0.f, 0.f};
  if (wave + 4 < nch) nxt = ldchunk(Arow, K, wave + 4, lane);

  for (int c = wave; c < nch; c += 4) {
    f32x4 a = cur;
    cur = nxt;
    if (c + 8 < nch) nxt = ldchunk(Arow, K, c + 8, lane);  // keep 2 in flight

    const int k = (c << 8) + lane * 4;
    const int n0 = (a[0] != 0.f), n1 = (a[1] != 0.f);
    const int n2 = (a[2] != 0.f), n3 = (a[3] != 0.f);
    const int cnt = n0 + n1 + n2 + n3;
    if (__ballot(cnt != 0) == 0ULL) continue;
    // inclusive prefix-scan of cnt across the wave
    int inc = cnt;
#pragma unroll
    for (int d = 1; d < 64; d <<= 1) {
      int t = __shfl_up(inc, d, 64);
      if (lane >= d) inc += t;
    }
    const int total = __shfl(inc, 63, 64);
    int p = inc - cnt;
    if (n0) { L[p] = make_uint2(k,     __float_as_uint(a[0])); p++; }
    if (n1) { L[p] = make_uint2(k + 1, __float_as_uint(a[1])); p++; }
    if (n2) { L[p] = make_uint2(k + 2, __float_as_uint(a[2])); p++; }
    if (n3) { L[p] = make_uint2(k + 3, __float_as_uint(a[3])); p++; }
    // wave-local visibility of this wave's ds_writes (lgkm only; the global
    // prefetches ride on vmcnt and are NOT drained here)
    asm volatile("s_waitcnt lgkmcnt(0)" ::: "memory");
    int e = 0;
    for (; e + 8 <= total; e += 8) {
      uint2 E0 = L[e],     E1 = L[e + 1], E2 = L[e + 2], E3 = L[e + 3];
      uint2 E4 = L[e + 4], E5 = L[e + 5], E6 = L[e + 6], E7 = L[e + 7];
      float x0 = X[(E0.x << 6) | lane];
      float x1 = X[(E1.x << 6) | lane];
      float x2 = X[(E2.x << 6) | lane];
      float x3 = X[(E3.x << 6) | lane];
      float x4 = X[(E4.x << 6) | lane];
      float x5 = X[(E5.x << 6) | lane];
      float x6 = X[(E6.x << 6) | lane];
      float x7 = X[(E7.x << 6) | lane];
      acc0 = fmaf(__uint_as_float(E0.y), x0, acc0);
      acc1 = fmaf(__uint_as_float(E1.y), x1, acc1);
      acc2 = fmaf(__uint_as_float(E2.y), x2, acc2);
      acc3 = fmaf(__uint_as_float(E3.y), x3, acc3);
      acc0 = fmaf(__uint_as_float(E4.y), x4, acc0);
      acc1 = fmaf(__uint_as_float(E5.y), x5, acc1);
      acc2 = fmaf(__uint_as_float(E6.y), x6, acc2);
      acc3 = fmaf(__uint_as_float(E7.y), x7, acc3);
    }
    for (; e < total; ++e) {
      uint2 E = L[e];
      acc0 = fmaf(__uint_as_float(E.y), X[(E.x << 6) | lane], acc0);
    }
  }
  return (acc0 + acc1) + (acc2 + acc3);
}

// items0 = relu(A_i@itf) + relu(B_i@itf) + itf. One block per row (3072).
__global__ __launch_bounds__(256) void spmm_items0(const float* __restrict__ Ai,
                                                   const float* __restrict__ Bi,
                                                   const float* __restrict__ itf,
                                                   float* __restrict__ items0)
{
  __shared__ uint2 lists[4][256];
  __shared__ float red[4][2][64];
  const int r = blockIdx.x;
  const int lane = threadIdx.x & 63, wave = threadIdx.x >> 6;
  float sa = spseg(Ai + (size_t)r * 3072, 3072, itf, lane, wave, lists[wave]);
  float sb = spseg(Bi + (size_t)r * 3072, 3072, itf, lane, wave, lists[wave]);
  red[wave][0][lane] = sa;
  red[wave][1][lane] = sb;
  __syncthreads();
  if (threadIdx.x < 64) {
    float a1 = red[0][0][lane] + red[1][0][lane] + red[2][0][lane] + red[3][0][lane];
    float a2 = red[0][1][lane] + red[1][1][lane] + red[2][1][lane] + red[3][1][lane];
    items0[(size_t)r * 64 + lane] =
        fmaxf(a1, 0.f) + fmaxf(a2, 0.f) + itf[(size_t)r * 64 + lane];
  }
}

// P = bi_avg@items; bundles_f = relu(P)+bfeat -> fub0 rows 6000+; b1 = l2norm(relu(P));
// fused: f0W row 6000+r = bundles_f_row @ W_ub.
__global__ __launch_bounds__(256) void spmm_bundle(const float* __restrict__ biA,
                                                   const float* __restrict__ items,
                                                   const float* __restrict__ bfeat,
                                                   const float* __restrict__ W_ub,
                                                   float* __restrict__ fub0,
                                                   float* __restrict__ b1,
                                                   float* __restrict__ f0W)
{
  __shared__ uint2 lists[4][256];
  __shared__ float red[4][64];
  __shared__ float rowsh[64];
  const int r = blockIdx.x;
  const int lane = threadIdx.x & 63, wave = threadIdx.x >> 6;
  float s = spseg(biA + (size_t)r * 3072, 3072, items, lane, wave, lists[wave]);
  red[wave][lane] = s;
  __syncthreads();
  if (threadIdx.x < 64) {
    float acc = red[0][lane] + red[1][lane] + red[2][lane] + red[3][lane];
    float pv = fmaxf(acc, 0.f);
    float fv = pv + bfeat[(size_t)r * 64 + lane];
    fub0[(size_t)(6000 + r) * 64 + lane] = fv;
    float n2 = wsum64(pv * pv);
    b1[(size_t)r * 64 + lane] = pv / fmaxf(sqrtf(n2), 1e-12f);
    rowsh[lane] = fv;
    asm volatile("s_waitcnt lgkmcnt(0)" ::: "memory");
    float w0 = 0.f, w1 = 0.f;
#pragma unroll
    for (int k = 0; k < 64; k += 2) {
      w0 = fmaf(rowsh[k],     W_ub[k * 64 + lane],       w0);
      w1 = fmaf(rowsh[k + 1], W_ub[(k + 1) * 64 + lane], w1);
    }
    f0W[(size_t)(6000 + r) * 64 + lane] = w0 + w1;
  }
}

// users_f = relu(ui_avg@items) + relu(ub_avg@bundles_f) + ufeat -> fub0 rows 0..5999;
// fused: f0W row r = users_f_row @ W_ub.
__global__ __launch_bounds__(256) void spmm_users(const float* __restrict__ uiA,
                                                  const float* __restrict__ ubA,
                                                  const float* __restrict__ items,
                                                  const float* __restrict__ bundles_f,
                                                  const float* __restrict__ ufeat,
                                                  const float* __restrict__ W_ub,
                                                  float* __restrict__ fub0,
                                                  float* __restrict__ f0W)
{
  __shared__ uint2 lists[4][256];
  __shared__ float red[4][2][64];
  __shared__ float rowsh[64];
  const int r = blockIdx.x;
  const int lane = threadIdx.x & 63, wave = threadIdx.x >> 6;
  float sa = spseg(uiA + (size_t)r * 3072, 3072, items, lane, wave, lists[wave]);
  float sb = spseg(ubA + (size_t)r * 3000, 3000, bundles_f, lane, wave, lists[wave]);
  red[wave][0][lane] = sa;
  red[wave][1][lane] = sb;
  __syncthreads();
  if (threadIdx.x < 64) {
    float a1 = red[0][0][lane] + red[1][0][lane] + red[2][0][lane] + red[3][0][lane];
    float a2 = red[0][1][lane] + red[1][1][lane] + red[2][1][lane] + red[3][1][lane];
    float fv = fmaxf(a1, 0.f) + fmaxf(a2, 0.f) + ufeat[(size_t)r * 64 + lane];
    fub0[(size_t)r * 64 + lane] = fv;
    rowsh[lane] = fv;
    asm volatile("s_waitcnt lgkmcnt(0)" ::: "memory");
    float w0 = 0.f, w1 = 0.f;
#pragma unroll
    for (int k = 0; k < 64; k += 2) {
      w0 = fmaf(rowsh[k],     W_ub[k * 64 + lane],       w0);
      w1 = fmaf(rowsh[k + 1], W_ub[(k + 1) * 64 + lane], w1);
    }
    f0W[(size_t)r * 64 + lane] = w0 + w1;
  }
}

// f_ub row = relu(ubg@f0W + b_ub); att2 fuse; joint l2norm; all_ub assembly.
__global__ __launch_bounds__(256) void spmm_ubg(const float* __restrict__ ubg,
                                                const float* __restrict__ f0W,
                                                const float* __restrict__ b_ub,
                                                const float* __restrict__ fub0,
                                                const float* __restrict__ b1,
                                                const float* __restrict__ att_w,
                                                float* __restrict__ all_ub)
{
  __shared__ uint2 lists[4][256];
  __shared__ float red[4][64];
  const int r = blockIdx.x;
  const int lane = threadIdx.x & 63, wave = threadIdx.x >> 6;
  float s = spseg(ubg + (size_t)r * 9000, 9000, f0W, lane, wave, lists[wave]);
  red[wave][lane] = s;
  __syncthreads();
  if (threadIdx.x < 64) {
    float acc = red[0][lane] + red[1][lane] + red[2][lane] + red[3][lane];
    float fu = fmaxf(acc + b_ub[lane], 0.f);
    float x0 = fub0[(size_t)r * 64 + lane];
    float x1 = (r < 6000) ? x0 : b1[(size_t)(r - 6000) * 64 + lane];
    float wv = att_w[lane];
    float s0 = wsum64(x0 * wv);
    float s1 = wsum64(x1 * wv);
    float m = fmaxf(s0, s1);
    float e0 = __expf(s0 - m), e1 = __expf(s1 - m);
    float fused = (e0 * x0 + e1 * x1) / (e0 + e1);
    float n2 = wsum64(fu * fu + fused * fused);
    float inv = 1.f / fmaxf(sqrtf(n2), 1e-12f);
    float* row = &all_ub[(size_t)r * 192];
    row[lane]       = x0;
    row[64 + lane]  = fu * inv;
    row[128 + lane] = fused * inv;
  }
}

// C[M x 64] = A[M x 64] @ W[64 x 64]; 4 rows/block; A row staged in LDS.
__global__ __launch_bounds__(256) void rowgemm64(const float* __restrict__ A,
                                                 const float* __restrict__ W,
                                                 float* __restrict__ C, int M)
{
  __shared__ float Ws[64][64];
  __shared__ float As[4][64];
  for (int i = threadIdx.x; i < 1024; i += 256)
    ((f32x4*)&Ws[0][0])[i] = ((const f32x4*)W)[i];
  const int wave = threadIdx.x >> 6, lane = threadIdx.x & 63;
  const int r = blockIdx.x * 4 + wave;
  const bool valid = r < M;
  As[wave][lane] = valid ? A[(size_t)r * 64 + lane] : 0.f;
  __syncthreads();
  float acc = 0.f;
#pragma unroll
  for (int k = 0; k < 64; ++k)
    acc = fmaf(As[wave][k], Ws[k][lane], acc);
  if (valid) C[(size_t)r * 64 + lane] = acc;
}

// Q,K,V projections in one dispatch (blockIdx.y selects weight/output).
__global__ __launch_bounds__(256) void rowgemm64_qkv(const float* __restrict__ A,
                                                     const float* __restrict__ Wq,
                                                     const float* __restrict__ Wk,
                                                     const float* __restrict__ Wv,
                                                     float* __restrict__ qb,
                                                     float* __restrict__ kb,
                                                     float* __restrict__ vb)
{
  const float* W = (blockIdx.y == 0) ? Wq : (blockIdx.y == 1) ? Wk : Wv;
  float* C = (blockIdx.y == 0) ? qb : (blockIdx.y == 1) ? kb : vb;
  __shared__ float Ws[64][64];
  __shared__ float As[4][64];
  for (int i = threadIdx.x; i < 1024; i += 256)
    ((f32x4*)&Ws[0][0])[i] = ((const f32x4*)W)[i];
  const int wave = threadIdx.x >> 6, lane = threadIdx.x & 63;
  const int r = blockIdx.x * 4 + wave;
  As[wave][lane] = A[(size_t)r * 64 + lane];
  __syncthreads();
  float acc = 0.f;
#pragma unroll
  for (int k = 0; k < 64; ++k)
    acc = fmaf(As[wave][k], Ws[k][lane], acc);
  C[(size_t)r * 64 + lane] = acc;
}

// Flash attention: 8 heads, dh=8, n=3072. grid (96, 8), block 256 = 32 queries x 8 parts.
// Batched: per 256-key LDS block, each part computes its 32 scores into registers,
// takes a block max, and does ONE rescale + 32-wide weighted PV accumulate.
__global__ __launch_bounds__(256) void attn_kernel(const float* __restrict__ q,
                                                   const float* __restrict__ k,
                                                   const float* __restrict__ v,
                                                   float* __restrict__ o)
{
  __shared__ float Ks[256][8];
  __shared__ float Vs[256][8];
  const int h = blockIdx.y;
  const int tid = threadIdx.x;
  const int qi = tid >> 3, p = tid & 7;
  const int n = blockIdx.x * 32 + qi;

  float qr[8];
#pragma unroll
  for (int j = 0; j < 8; ++j) qr[j] = q[n * 64 + h * 8 + j] * 0.3535533905932738f;

  float mx = -1e30f, sum = 0.f, acc[8] = {};

  for (int m0 = 0; m0 < 3072; m0 += 256) {
    __syncthreads();
    {
      const float* kp = &k[(size_t)(m0 + tid) * 64 + h * 8];
      const float* vp = &v[(size_t)(m0 + tid) * 64 + h * 8];
      float4 a0 = *reinterpret_cast<const float4*>(kp);
      float4 a1 = *reinterpret_cast<const float4*>(kp + 4);
      float4 b0 = *reinterpret_cast<const float4*>(vp);
      float4 b1 = *reinterpret_cast<const float4*>(vp + 4);
      *reinterpret_cast<float4*>(&Ks[tid][0]) = a0;
      *reinterpret_cast<float4*>(&Ks[tid][4]) = a1;
      *reinterpret_cast<float4*>(&Vs[tid][0]) = b0;
      *reinterpret_cast<float4*>(&Vs[tid][4]) = b1;
    }
    __syncthreads();

    float s[32];
#pragma unroll
    for (int i = 0; i < 32; ++i) {
      const int mm = p + i * 8;
      float t = 0.f;
#pragma unroll
      for (int j = 0; j < 8; ++j) t = fmaf(qr[j], Ks[mm][j], t);
      s[i] = t;
    }
    float lmax = s[0];
#pragma unroll
    for (int i = 1; i < 32; ++i) lmax = fmaxf(lmax, s[i]);
    const float nm = fmaxf(mx, lmax);
    const float corr = __expf(mx - nm);
    sum *= corr;
#pragma unroll
    for (int j = 0; j < 8; ++j) acc[j] *= corr;
#pragma unroll
    for (int i = 0; i < 32; ++i) {
      const int mm = p + i * 8;
      const float w = __expf(s[i] - nm);
      sum += w;
#pragma unroll
      for (int j = 0; j < 8; ++j) acc[j] = fmaf(w, Vs[mm][j], acc[j]);
    }
    mx = nm;
  }
  // merge the 8 partials (lanes differing in bits 0..2 share a query)
#pragma unroll
  for (int d = 1; d < 8; d <<= 1) {
    float omx = __shfl_xor(mx, d, 64);
    float osum = __shfl_xor(sum, d, 64);
    float nm = fmaxf(mx, omx);
    float c1 = __expf(mx - nm), c2 = __expf(omx - nm);
    float nsum = sum * c1 + osum * c2;
#pragma unroll
    for (int j = 0; j < 8; ++j) {
      float oa = __shfl_xor(acc[j], d, 64);
      acc[j] = acc[j] * c1 + oa * c2;
    }
    mx = nm; sum = nsum;
  }
  if (p == 0) {
    float inv = 1.f / sum;
#pragma unroll
    for (int j = 0; j < 8; ++j) o[n * 64 + h * 8 + j] = acc[j] * inv;
  }
}

// Final gather + 576->8 relu MLP -> 1. One wave per batch row. grid 1024, block 256.
__global__ __launch_bounds__(256) void final_mlp(const float* __restrict__ all_ub,
                                                 const int* __restrict__ users,
                                                 const int* __restrict__ bundles,
                                                 const float* __restrict__ p1W,
                                                 const float* __restrict__ p1b,
                                                 const float* __restrict__ p2W,
                                                 const float* __restrict__ p2b,
                                                 float* __restrict__ out)
{
  __shared__ float W[576 * 8];
  for (int i = threadIdx.x; i < 576 * 8; i += 256) W[i] = p1W[i];
  __syncthreads();
  int j = blockIdx.x * 4 + (threadIdx.x >> 6);
  int lane = threadIdx.x & 63;
  const float* ue = &all_ub[(size_t)users[j] * 192];
  const float* be = &all_ub[(size_t)(6000 + bundles[j]) * 192];
  float hacc[8] = {};
#pragma unroll
  for (int db = 0; db < 9; ++db) {
    int d = db * 64 + lane;
    float ne;
    if (d < 192)      ne = ue[d] * be[d];
    else if (d < 384) ne = be[d - 192];
    else              ne = ue[d - 384];
#pragma unroll
    for (int h = 0; h < 8; ++h) hacc[h] = fmaf(ne, W[d * 8 + h], hacc[h]);
  }
#pragma unroll
  for (int d = 1; d < 64; d <<= 1)
#pragma unroll
    for (int h = 0; h < 8; ++h) hacc[h] += __shfl_xor(hacc[h], d, 64);
  if (lane == 0) {
    float o = p2b[0];
#pragma unroll
    for (int h = 0; h < 8; ++h) o += fmaxf(hacc[h] + p1b[h], 0.f) * p2W[h];
    out[j] = o;
  }
}

extern "C" void kernel_launch(void* const* d_in, const int* in_sizes, int n_in,
                              void* d_out, int out_size, void* d_ws, size_t ws_size,
                              hipStream_t stream)
{
  const float* ufeat   = (const float*)d_in[0];
  const float* ifeat   = (const float*)d_in[1];
  const float* bfeat   = (const float*)d_in[2];
  const float* Wq      = (const float*)d_in[3];
  const float* Wk      = (const float*)d_in[4];
  const float* Wv      = (const float*)d_in[5];
  const float* Wo      = (const float*)d_in[6];
  const float* W_ub    = (const float*)d_in[7];
  const float* b_ub    = (const float*)d_in[8];
  const float* att_b_w = (const float*)d_in[11];
  const float* p1W     = (const float*)d_in[13];
  const float* p1b     = (const float*)d_in[14];
  const float* p2W     = (const float*)d_in[15];
  const float* p2b     = (const float*)d_in[16];
  const float* A_i     = (const float*)d_in[17];
  const float* B_i     = (const float*)d_in[18];
  const float* bi_avg  = (const float*)d_in[19];
  const float* ui_avg  = (const float*)d_in[20];
  const float* ub_avg  = (const float*)d_in[21];
  const float* ubg     = (const float*)d_in[23];
  const int* users     = (const int*)d_in[25];
  const int* bundles   = (const int*)d_in[26];

  float* ws = (float*)d_ws;
  float* items0 = ws;  ws += 3072 * 64;
  float* qb     = ws;  ws += 3072 * 64;
  float* kb     = ws;  ws += 3072 * 64;
  float* vb     = ws;  ws += 3072 * 64;
  float* attnb  = ws;  ws += 3072 * 64;
  float* items  = ws;  ws += 3072 * 64;
  float* b1     = ws;  ws += 3000 * 64;
  float* fub0   = ws;  ws += 9000 * 64;   // users_f rows 0..5999, bundles_f 6000..8999
  float* f0W    = ws;  ws += 9000 * 64;   // fub0 @ W_ub
  float* all_ub = ws;  ws += 9000 * 192;

  // items0 = relu(A_i@itf) + relu(B_i@itf) + itf
  spmm_items0<<<3072, 256, 0, stream>>>(A_i, B_i, ifeat, items0);

  // multi-head attention
  rowgemm64_qkv<<<dim3(768, 3), 256, 0, stream>>>(items0, Wq, Wk, Wv, qb, kb, vb);
  attn_kernel<<<dim3(96, 8), 256, 0, stream>>>(qb, kb, vb, attnb);
  rowgemm64<<<768, 256, 0, stream>>>(attnb, Wo, items, 3072);

  // bundles_f (+ b1, + f0W rows 6000+), then users_f (+ f0W rows 0..5999)
  spmm_bundle<<<3000, 256, 0, stream>>>(bi_avg, items, bfeat, W_ub, fub0, b1, f0W);
  spmm_users<<<6000, 256, 0, stream>>>(ui_avg, ub_avg, items,
                                       fub0 + (size_t)6000 * 64, ufeat, W_ub,
                                       fub0, f0W);

  // ubg row product + bias/relu + att2 fuse + joint l2norm + all_ub assembly
  spmm_ubg<<<9000, 256, 0, stream>>>(ubg, f0W, b_ub, fub0, b1, att_b_w, all_ub);

  // gather + final MLP
  final_mlp<<<1024, 256, 0, stream>>>(all_ub, users, bundles, p1W, p1b, p2W, p2b,
                                      (float*)d_out);
}